// Round 1
// baseline (3793.303 us; speedup 1.0000x reference)
//
#include <hip/hip_runtime.h>
#include <hip/hip_bf16.h>

#define BN_EPS 1e-5f
#define SQ_EPS 1e-8f

// Problem sizes (fixed by setup_inputs)
// features (64,512,28,28), conv1_w (256,512,3,3), prim_w (256,256,9,9),
// route_w (800,2,16,32). lower_caps (64,800,32), v (64,2,16).

// ---------------- weight transposes (one-time per call, tiny) -------------
__global__ void transpose_w1(const float* __restrict__ w, float* __restrict__ wt) {
    int idx = blockIdx.x * 256 + threadIdx.x;  // total 512*9*256
    if (idx >= 512 * 9 * 256) return;
    int co = idx & 255;
    int k  = (idx >> 8) % 9;
    int ci = (idx >> 8) / 9;
    wt[idx] = w[(co * 512 + ci) * 9 + k];      // wt[ci][k][co]
}

__global__ void transpose_w2(const float* __restrict__ w, float* __restrict__ wt) {
    int idx = blockIdx.x * 256 + threadIdx.x;  // total 256*81*256
    if (idx >= 256 * 81 * 256) return;
    int co = idx & 255;
    int k  = (idx >> 8) % 81;
    int ci = (idx >> 8) / 81;
    wt[idx] = w[(co * 256 + ci) * 81 + k];     // wt[ci][k][co]
}

// ---------------- conv1 + bias + BN(eval) + ReLU --------------------------
// grid (7 rowTiles, 4 coTiles, 64 b), block 256 = 64 co-lanes x 4 rows
__global__ __launch_bounds__(256) void conv1_kernel(
    const float* __restrict__ feat, const float* __restrict__ wt,
    const float* __restrict__ bias, const float* __restrict__ gamma,
    const float* __restrict__ beta, const float* __restrict__ mean,
    const float* __restrict__ var, float* __restrict__ out) {
    const int b    = blockIdx.z;
    const int coT  = blockIdx.y;
    const int rowT = blockIdx.x;
    const int lane = threadIdx.x & 63;
    const int co   = coT * 64 + lane;
    const int r    = threadIdx.x >> 6;   // 0..3 (wave-uniform)
    const int h    = rowT * 4 + r;

    __shared__ float lds[6][32];
    float acc[28];
#pragma unroll
    for (int i = 0; i < 28; i++) acc[i] = 0.f;

    for (int ci = 0; ci < 512; ci++) {
        __syncthreads();
        if (threadIdx.x < 192) {
            int rr = threadIdx.x >> 5, cc = threadIdx.x & 31;
            int ih = rowT * 4 - 1 + rr, iw = cc - 1;
            float v = 0.f;
            if (ih >= 0 && ih < 28 && (unsigned)iw < 28u)
                v = feat[((b * 512 + ci) * 28 + ih) * 28 + iw];
            lds[rr][cc] = v;
        }
        __syncthreads();
        float wk[9];
#pragma unroll
        for (int k = 0; k < 9; k++) wk[k] = wt[(ci * 9 + k) * 256 + co];
        float rowreg[3][30];
#pragma unroll
        for (int ky = 0; ky < 3; ky++)
#pragma unroll
            for (int c = 0; c < 30; c++) rowreg[ky][c] = lds[r + ky][c];
#pragma unroll
        for (int wo = 0; wo < 28; wo++)
#pragma unroll
            for (int ky = 0; ky < 3; ky++)
#pragma unroll
                for (int kx = 0; kx < 3; kx++)
                    acc[wo] = fmaf(wk[ky * 3 + kx], rowreg[ky][wo + kx], acc[wo]);
    }
    float inv   = gamma[co] * rsqrtf(var[co] + BN_EPS);
    float shift = beta[co] - mean[co] * inv;
    float bs    = bias[co];
#pragma unroll
    for (int wo = 0; wo < 28; wo++) {
        float v = (acc[wo] + bs) * inv + shift;
        out[((b * 256 + co) * 28 + h) * 28 + wo] = fmaxf(v, 0.f);
    }
}

// ---------------- conv2 (k9, s2, VALID) + bias ----------------------------
// grid (4 coTiles, 64 b), block 640 = 64 co-lanes x 10 output rows
__global__ __launch_bounds__(640) void conv2_kernel(
    const float* __restrict__ x, const float* __restrict__ wt,
    const float* __restrict__ bias, float* __restrict__ p) {
    const int b    = blockIdx.y;
    const int coT  = blockIdx.x;
    const int lane = threadIdx.x & 63;
    const int co   = coT * 64 + lane;
    const int ho   = threadIdx.x >> 6;  // 0..9 (wave-uniform)
    __shared__ float xs[784];
    float acc[10];
#pragma unroll
    for (int i = 0; i < 10; i++) acc[i] = 0.f;

    for (int ci = 0; ci < 256; ci++) {
        __syncthreads();
        for (int i = threadIdx.x; i < 784; i += 640)
            xs[i] = x[(b * 256 + ci) * 784 + i];
        __syncthreads();
        for (int ky = 0; ky < 9; ky++) {
            float wk[9];
#pragma unroll
            for (int k = 0; k < 9; k++) wk[k] = wt[(ci * 81 + ky * 9 + k) * 256 + co];
            float row[27];
#pragma unroll
            for (int c = 0; c < 27; c++) row[c] = xs[(2 * ho + ky) * 28 + c];
#pragma unroll
            for (int wo = 0; wo < 10; wo++)
#pragma unroll
                for (int kx = 0; kx < 9; kx++)
                    acc[wo] = fmaf(wk[kx], row[2 * wo + kx], acc[wo]);
        }
    }
    float bs = bias[co];
#pragma unroll
    for (int wo = 0; wo < 10; wo++)
        p[(b * 256 + co) * 100 + ho * 10 + wo] = acc[wo] + bs;
}

// ---------------- squash -> lower_caps (to d_out) -------------------------
// 32 lanes per capsule row; block 256 = 8 rows; grid 64*800/8
__global__ __launch_bounds__(256) void squash_kernel(
    const float* __restrict__ p, float* __restrict__ lc) {
    int rowg = blockIdx.x * 8 + (threadIdx.x >> 5);
    int i = threadIdx.x & 31;
    int b = rowg / 800, r = rowg - b * 800;
    int cap = r / 100, s = r - cap * 100;
    float val = p[(b * 256 + cap * 32 + i) * 100 + s];
    float n2 = val * val;
#pragma unroll
    for (int m = 1; m < 32; m <<= 1) n2 += __shfl_xor(n2, m);
    float scale = n2 / ((1.f + n2) * sqrtf(n2 + SQ_EPS));
    lc[(b * 800 + r) * 32 + i] = val * scale;
}

// ---------------- u_hat (transposed layout [b][j][o][r]) ------------------
// block 256 = 8 r x 32 (j,o); grid (100, 64)
__global__ __launch_bounds__(256) void uhat_kernel(
    const float* __restrict__ lc, const float* __restrict__ rw,
    float* __restrict__ uht) {
    int b  = blockIdx.y;
    int r  = blockIdx.x * 8 + (threadIdx.x >> 5);
    int jo = threadIdx.x & 31;
    const float4* lp4 = reinterpret_cast<const float4*>(lc + (b * 800 + r) * 32);
    const float4* wp4 = reinterpret_cast<const float4*>(rw + (r * 32 + jo) * 32);
    float acc = 0.f;
#pragma unroll
    for (int k = 0; k < 8; k++) {
        float4 a = lp4[k], w = wp4[k];
        acc = fmaf(a.x, w.x, acc);
        acc = fmaf(a.y, w.y, acc);
        acc = fmaf(a.z, w.z, acc);
        acc = fmaf(a.w, w.w, acc);
    }
    uht[(b * 32 + jo) * 800 + r] = acc;
}

// ---------------- routing: c -> s -> v (one block per (b,j)) --------------
__global__ __launch_bounds__(256) void route_sv_kernel(
    const float* __restrict__ uht, const float* __restrict__ bc,
    float* __restrict__ vbuf, float* __restrict__ vout,
    int first_iter, int write_out) {
    int b = blockIdx.y, j = blockIdx.x;
    int tid = threadIdx.x;
    float sp[16];
#pragma unroll
    for (int o = 0; o < 16; o++) sp[o] = 0.f;
    const float* u0 = uht + (b * 32 + j * 16) * 800;
    for (int r = tid; r < 800; r += 256) {
        float c;
        if (first_iter) {
            c = 0.5f;
        } else {
            float b0 = bc[(b * 800 + r) * 2 + 0];
            float b1 = bc[(b * 800 + r) * 2 + 1];
            float m  = fmaxf(b0, b1);
            float e0 = __expf(b0 - m), e1 = __expf(b1 - m);
            c = (j == 0 ? e0 : e1) / (e0 + e1);
        }
#pragma unroll
        for (int o = 0; o < 16; o++) sp[o] += c * u0[o * 800 + r];
    }
#pragma unroll
    for (int o = 0; o < 16; o++)
#pragma unroll
        for (int m = 1; m < 64; m <<= 1) sp[o] += __shfl_xor(sp[o], m);
    __shared__ float red[4][16];
    int wave = tid >> 6;
    if ((tid & 63) == 0)
#pragma unroll
        for (int o = 0; o < 16; o++) red[wave][o] = sp[o];
    __syncthreads();
    if (tid == 0) {
        float s[16];
        float n2 = 0.f;
#pragma unroll
        for (int o = 0; o < 16; o++) {
            s[o] = red[0][o] + red[1][o] + red[2][o] + red[3][o];
            n2 += s[o] * s[o];
        }
        float scale = n2 / ((1.f + n2) * sqrtf(n2 + SQ_EPS));
#pragma unroll
        for (int o = 0; o < 16; o++) {
            float v = s[o] * scale;
            vbuf[(b * 2 + j) * 16 + o] = v;
            if (write_out) vout[(b * 2 + j) * 16 + o] = v;
        }
    }
}

// ---------------- routing: b += u_hat . v (one block per b) ---------------
__global__ __launch_bounds__(256) void route_bupd_kernel(
    const float* __restrict__ uht, const float* __restrict__ vbuf,
    float* __restrict__ bc) {
    int b = blockIdx.x;
    __shared__ float vs[32];
    if (threadIdx.x < 32) vs[threadIdx.x] = vbuf[b * 32 + threadIdx.x];
    __syncthreads();
    for (int r = threadIdx.x; r < 800; r += 256) {
#pragma unroll
        for (int j = 0; j < 2; j++) {
            float a = 0.f;
#pragma unroll
            for (int o = 0; o < 16; o++)
                a = fmaf(uht[(b * 32 + j * 16 + o) * 800 + r], vs[j * 16 + o], a);
            bc[(b * 800 + r) * 2 + j] += a;
        }
    }
}

extern "C" void kernel_launch(void* const* d_in, const int* in_sizes, int n_in,
                              void* d_out, int out_size, void* d_ws, size_t ws_size,
                              hipStream_t stream) {
    const float* feat    = (const float*)d_in[0];
    const float* conv1_w = (const float*)d_in[1];
    const float* conv1_b = (const float*)d_in[2];
    const float* bn_g    = (const float*)d_in[3];
    const float* bn_b    = (const float*)d_in[4];
    const float* bn_m    = (const float*)d_in[5];
    const float* bn_v    = (const float*)d_in[6];
    const float* prim_w  = (const float*)d_in[7];
    const float* prim_b  = (const float*)d_in[8];
    const float* route_w = (const float*)d_in[9];
    float* out = (float*)d_out;

    // ws layout (floats)
    float* ws   = (float*)d_ws;
    float* x    = ws;                    // 64*256*28*28 = 12845056
    float* p    = x + 12845056;          // 64*256*100   = 1638400
    float* wt1  = p + 1638400;           // 512*9*256    = 1179648
    float* wt2  = wt1 + 1179648;         // 256*81*256   = 5308416
    float* uht  = wt2 + 5308416;         // 64*2*16*800  = 1638400
    float* bc   = uht + 1638400;         // 64*800*2     = 102400
    float* vbuf = bc + 102400;           // 64*2*16      = 2048

    float* lc_out = out;                 // (64,800,32)
    float* v_out  = out + 64 * 800 * 32; // (64,2,16)

    transpose_w1<<<(512 * 9 * 256 + 255) / 256, 256, 0, stream>>>(conv1_w, wt1);
    transpose_w2<<<(256 * 81 * 256 + 255) / 256, 256, 0, stream>>>(prim_w, wt2);

    conv1_kernel<<<dim3(7, 4, 64), 256, 0, stream>>>(
        feat, wt1, conv1_b, bn_g, bn_b, bn_m, bn_v, x);

    conv2_kernel<<<dim3(4, 64), 640, 0, stream>>>(x, wt2, prim_b, p);

    squash_kernel<<<64 * 800 / 8, 256, 0, stream>>>(p, lc_out);

    uhat_kernel<<<dim3(100, 64), 256, 0, stream>>>(lc_out, route_w, uht);

    hipMemsetAsync(bc, 0, 64 * 800 * 2 * sizeof(float), stream);

    // it 0
    route_sv_kernel<<<dim3(2, 64), 256, 0, stream>>>(uht, bc, vbuf, v_out, 1, 0);
    route_bupd_kernel<<<64, 256, 0, stream>>>(uht, vbuf, bc);
    // it 1
    route_sv_kernel<<<dim3(2, 64), 256, 0, stream>>>(uht, bc, vbuf, v_out, 0, 0);
    route_bupd_kernel<<<64, 256, 0, stream>>>(uht, vbuf, bc);
    // it 2 (final, write v to d_out)
    route_sv_kernel<<<dim3(2, 64), 256, 0, stream>>>(uht, bc, vbuf, v_out, 0, 1);
}

// Round 2
// 432.102 us; speedup vs baseline: 8.7787x; 8.7787x over previous
//
#include <hip/hip_runtime.h>
#include <hip/hip_bf16.h>

#define BN_EPS 1e-5f
#define SQ_EPS 1e-8f

typedef __hip_bfloat16 bf16;
typedef __attribute__((ext_vector_type(8))) short bf16x8;
typedef __attribute__((ext_vector_type(4))) float f32x4;

// async global->LDS, 16B per lane; LDS dest is wave-uniform base + lane*16
__device__ __forceinline__ void gload_lds16(const void* g, void* l) {
    __builtin_amdgcn_global_load_lds(
        (const __attribute__((address_space(1))) unsigned int*)g,
        (__attribute__((address_space(3))) unsigned int*)l, 16, 0, 0);
}

// ---------------- feat NCHW fp32 -> padded NHWC bf16 ----------------------
// featP[64][30][30][512], border pre-zeroed by memset. grid (13,8,64) blk 256
__global__ __launch_bounds__(256) void feat_to_nhwc(
    const float* __restrict__ feat, bf16* __restrict__ featP) {
    int b = blockIdx.z, ct = blockIdx.y, pt = blockIdx.x;
    int ci0 = ct * 64, px0 = pt * 64;
    __shared__ float t[64][65];
#pragma unroll
    for (int rep = 0; rep < 16; rep++) {
        int ci_l = rep * 4 + (threadIdx.x >> 6);
        int px = px0 + (threadIdx.x & 63);
        float v = 0.f;
        if (px < 784) v = feat[(b * 512 + ci0 + ci_l) * 784 + px];
        t[ci_l][threadIdx.x & 63] = v;
    }
    __syncthreads();
#pragma unroll
    for (int rep = 0; rep < 16; rep++) {
        int px_l = rep * 4 + (threadIdx.x >> 6);
        int px = px0 + px_l;
        if (px < 784) {
            int h = px / 28, w = px % 28;
            int ci = threadIdx.x & 63;
            featP[((b * 30 + h + 1) * 30 + (w + 1)) * 512 + ci0 + ci] =
                __float2bfloat16(t[ci][px_l]);
        }
    }
}

// ---------------- conv1_w [co][ci][3][3] -> wt1 [kykx][co][ci] bf16 -------
__global__ __launch_bounds__(128) void w1_transform(
    const float* __restrict__ w, bf16* __restrict__ wt1) {
    int co = blockIdx.y, ci0 = blockIdx.x * 32;
    __shared__ float t[288];
    const float* src = w + (co * 512 + ci0) * 9;
    for (int i = threadIdx.x; i < 288; i += 128) t[i] = src[i];
    __syncthreads();
    for (int i = threadIdx.x; i < 288; i += 128) {
        int kykx = i >> 5, ci = i & 31;
        wt1[(kykx * 256 + co) * 512 + ci0 + ci] = __float2bfloat16(t[ci * 9 + kykx]);
    }
}

// ---------------- prim_w [co][ci][9][9] -> wt2 [kykx][co][ci] bf16 --------
__global__ __launch_bounds__(256) void w2_transform(
    const float* __restrict__ w, bf16* __restrict__ wt2) {
    int co = blockIdx.y, ci0 = blockIdx.x * 32;
    __shared__ float t[2592];
    const float* src = w + (co * 256 + ci0) * 81;
    for (int i = threadIdx.x; i < 2592; i += 256) t[i] = src[i];
    __syncthreads();
    for (int i = threadIdx.x; i < 2592; i += 256) {
        int kykx = i >> 5, ci = i & 31;   // 2592 = 81*32
        wt2[(kykx * 256 + co) * 256 + ci0 + ci] = __float2bfloat16(t[ci * 81 + kykx]);
    }
}

// ---------------- conv1 as implicit GEMM (MFMA bf16) ----------------------
// M=50176 (b,h,w raster), N=256 (co), K=9*512. Tile 128x128, BK=32, 4 waves.
// grid (392, 2) block 256.  Epilogue: +bias, BN, ReLU, write NHWC bf16 x.
__global__ __launch_bounds__(256) void conv1_mfma(
    const bf16* __restrict__ featP, const bf16* __restrict__ wt1,
    const float* __restrict__ bias, const float* __restrict__ gamma,
    const float* __restrict__ beta, const float* __restrict__ mean,
    const float* __restrict__ var, bf16* __restrict__ x) {
    __shared__ short As[2][4096];
    __shared__ short Bs[2][4096];
    const int tid = threadIdx.x, lane = tid & 63, w = tid >> 6;
    const int wr = w >> 1, wc = w & 1;
    const int Mt = blockIdx.x, Nt = blockIdx.y;

    // staging sources: wave w stages A rows [w*32,w*32+32) and same B rows.
    // instr j: row = w*32 + j*16 + (lane>>2); LDS write is linear, so the
    // GLOBAL source is pre-swizzled: q_src = (lane&3) ^ ((row>>1)&3).
    const bf16 *asrc0, *asrc1, *bsrc0, *bsrc1;
    {
        int rl0 = w * 32 + (lane >> 2);
        int rl1 = rl0 + 16;
        int q0 = (lane & 3) ^ ((rl0 >> 1) & 3);
        int q1 = (lane & 3) ^ ((rl1 >> 1) & 3);
        int m0 = Mt * 128 + rl0, m1 = Mt * 128 + rl1;
        int b0 = m0 / 784, r0 = m0 % 784, h0 = r0 / 28, w0 = r0 % 28;
        int b1 = m1 / 784, r1 = m1 % 784, h1 = r1 / 28, w1 = r1 % 28;
        asrc0 = featP + ((b0 * 30 + h0) * 30 + w0) * 512 + q0 * 8;
        asrc1 = featP + ((b1 * 30 + h1) * 30 + w1) * 512 + q1 * 8;
        int co0 = Nt * 128 + rl0, co1 = Nt * 128 + rl1;
        bsrc0 = wt1 + co0 * 512 + q0 * 8;
        bsrc1 = wt1 + co1 * 512 + q1 * 8;
    }

    // LDS read offsets (bytes), swizzled the same way
    int a_off[4], b_off[4];
#pragma unroll
    for (int mi = 0; mi < 4; mi++) {
        int r = wr * 64 + mi * 16 + (lane & 15);
        a_off[mi] = r * 64 + (((lane >> 4) ^ ((r >> 1) & 3)) * 16);
    }
#pragma unroll
    for (int nj = 0; nj < 4; nj++) {
        int r = wc * 64 + nj * 16 + (lane & 15);
        b_off[nj] = r * 64 + (((lane >> 4) ^ ((r >> 1) & 3)) * 16);
    }

    f32x4 acc[4][4];
#pragma unroll
    for (int i = 0; i < 4; i++)
#pragma unroll
        for (int j = 0; j < 4; j++) acc[i][j] = f32x4{0.f, 0.f, 0.f, 0.f};

#define C1_STAGE(bufi, kk)                                                  \
    do {                                                                    \
        int kykx = (kk) >> 4;                                               \
        int ci0_ = ((kk) & 15) << 5;                                        \
        int ky_ = kykx / 3, kx_ = kykx - ky_ * 3;                           \
        int aoffE = (ky_ * 30 + kx_) * 512 + ci0_;                          \
        int boffE = kykx * 131072 + ci0_;                                   \
        short* ab = &As[bufi][w * 1024];                                    \
        short* bb = &Bs[bufi][w * 1024];                                    \
        gload_lds16(asrc0 + aoffE, ab);                                     \
        gload_lds16(asrc1 + aoffE, ab + 512);                               \
        gload_lds16(bsrc0 + boffE, bb);                                     \
        gload_lds16(bsrc1 + boffE, bb + 512);                               \
    } while (0)

    C1_STAGE(0, 0);
    __syncthreads();
    int buf = 0;
    for (int kk = 0; kk < 144; kk++) {
        if (kk + 1 < 144) C1_STAGE(buf ^ 1, kk + 1);
        bf16x8 af[4], bfr[4];
#pragma unroll
        for (int mi = 0; mi < 4; mi++)
            af[mi] = *(const bf16x8*)((const char*)As[buf] + a_off[mi]);
#pragma unroll
        for (int nj = 0; nj < 4; nj++)
            bfr[nj] = *(const bf16x8*)((const char*)Bs[buf] + b_off[nj]);
#pragma unroll
        for (int mi = 0; mi < 4; mi++)
#pragma unroll
            for (int nj = 0; nj < 4; nj++)
                acc[mi][nj] = __builtin_amdgcn_mfma_f32_16x16x32_bf16(
                    af[mi], bfr[nj], acc[mi][nj], 0, 0, 0);
        __syncthreads();
        buf ^= 1;
    }

    // epilogue: C row m = Mt*128+wr*64+mi*16+(lane>>4)*4+r, col co
#pragma unroll
    for (int nj = 0; nj < 4; nj++) {
        int co = Nt * 128 + wc * 64 + nj * 16 + (lane & 15);
        float inv = gamma[co] * rsqrtf(var[co] + BN_EPS);
        float sh = beta[co] - mean[co] * inv;
        float bs = bias[co];
#pragma unroll
        for (int mi = 0; mi < 4; mi++) {
            int m0 = Mt * 128 + wr * 64 + mi * 16 + ((lane >> 4) << 2);
#pragma unroll
            for (int r = 0; r < 4; r++) {
                float v = (acc[mi][nj][r] + bs) * inv + sh;
                x[(m0 + r) * 256 + co] = __float2bfloat16(fmaxf(v, 0.f));
            }
        }
    }
}

// ---------------- conv2 (k9 s2) as implicit GEMM, split-K=8 ---------------
// M=6400 (b,ho,wo), N=256, K=81*256. grid (50, 2, 8) block 256.
__global__ __launch_bounds__(256) void conv2_mfma(
    const bf16* __restrict__ x, const bf16* __restrict__ wt2,
    bf16* __restrict__ p_parts) {
    __shared__ short As[2][4096];
    __shared__ short Bs[2][4096];
    const int tid = threadIdx.x, lane = tid & 63, w = tid >> 6;
    const int wr = w >> 1, wc = w & 1;
    const int Mt = blockIdx.x, Nt = blockIdx.y, z = blockIdx.z;
    const int sh0 = (81 * z) / 8, sh1 = (81 * (z + 1)) / 8;
    const int nsteps = (sh1 - sh0) * 8;

    const bf16 *asrc0, *asrc1, *bsrc0, *bsrc1;
    {
        int rl0 = w * 32 + (lane >> 2);
        int rl1 = rl0 + 16;
        int q0 = (lane & 3) ^ ((rl0 >> 1) & 3);
        int q1 = (lane & 3) ^ ((rl1 >> 1) & 3);
        int m0 = Mt * 128 + rl0, m1 = Mt * 128 + rl1;
        int b0 = m0 / 100, s0 = m0 % 100, ho0 = s0 / 10, wo0 = s0 % 10;
        int b1 = m1 / 100, s1 = m1 % 100, ho1 = s1 / 10, wo1 = s1 % 10;
        asrc0 = x + ((b0 * 28 + 2 * ho0) * 28 + 2 * wo0) * 256 + q0 * 8;
        asrc1 = x + ((b1 * 28 + 2 * ho1) * 28 + 2 * wo1) * 256 + q1 * 8;
        int co0 = Nt * 128 + rl0, co1 = Nt * 128 + rl1;
        bsrc0 = wt2 + co0 * 256 + q0 * 8;
        bsrc1 = wt2 + co1 * 256 + q1 * 8;
    }

    int a_off[4], b_off[4];
#pragma unroll
    for (int mi = 0; mi < 4; mi++) {
        int r = wr * 64 + mi * 16 + (lane & 15);
        a_off[mi] = r * 64 + (((lane >> 4) ^ ((r >> 1) & 3)) * 16);
    }
#pragma unroll
    for (int nj = 0; nj < 4; nj++) {
        int r = wc * 64 + nj * 16 + (lane & 15);
        b_off[nj] = r * 64 + (((lane >> 4) ^ ((r >> 1) & 3)) * 16);
    }

    f32x4 acc[4][4];
#pragma unroll
    for (int i = 0; i < 4; i++)
#pragma unroll
        for (int j = 0; j < 4; j++) acc[i][j] = f32x4{0.f, 0.f, 0.f, 0.f};

#define C2_STAGE(bufi, kk)                                                  \
    do {                                                                    \
        int sh_ = sh0 + ((kk) >> 3);                                        \
        int ci0_ = ((kk) & 7) << 5;                                         \
        int ky_ = sh_ / 9, kx_ = sh_ - ky_ * 9;                             \
        int aoffE = (ky_ * 28 + kx_) * 256 + ci0_;                          \
        int boffE = sh_ * 65536 + ci0_;                                     \
        short* ab = &As[bufi][w * 1024];                                    \
        short* bb = &Bs[bufi][w * 1024];                                    \
        gload_lds16(asrc0 + aoffE, ab);                                     \
        gload_lds16(asrc1 + aoffE, ab + 512);                               \
        gload_lds16(bsrc0 + boffE, bb);                                     \
        gload_lds16(bsrc1 + boffE, bb + 512);                               \
    } while (0)

    C2_STAGE(0, 0);
    __syncthreads();
    int buf = 0;
    for (int kk = 0; kk < nsteps; kk++) {
        if (kk + 1 < nsteps) C2_STAGE(buf ^ 1, kk + 1);
        bf16x8 af[4], bfr[4];
#pragma unroll
        for (int mi = 0; mi < 4; mi++)
            af[mi] = *(const bf16x8*)((const char*)As[buf] + a_off[mi]);
#pragma unroll
        for (int nj = 0; nj < 4; nj++)
            bfr[nj] = *(const bf16x8*)((const char*)Bs[buf] + b_off[nj]);
#pragma unroll
        for (int mi = 0; mi < 4; mi++)
#pragma unroll
            for (int nj = 0; nj < 4; nj++)
                acc[mi][nj] = __builtin_amdgcn_mfma_f32_16x16x32_bf16(
                    af[mi], bfr[nj], acc[mi][nj], 0, 0, 0);
        __syncthreads();
        buf ^= 1;
    }

#pragma unroll
    for (int nj = 0; nj < 4; nj++) {
        int co = Nt * 128 + wc * 64 + nj * 16 + (lane & 15);
#pragma unroll
        for (int mi = 0; mi < 4; mi++) {
            int m0 = Mt * 128 + wr * 64 + mi * 16 + ((lane >> 4) << 2);
#pragma unroll
            for (int r = 0; r < 4; r++)
                p_parts[(z * 6400 + m0 + r) * 256 + co] =
                    __float2bfloat16(acc[mi][nj][r]);
        }
    }
}

// ---------------- squash: sum split-K parts + bias -> lower_caps ----------
__global__ __launch_bounds__(256) void squash_kernel(
    const bf16* __restrict__ pp, const float* __restrict__ pb,
    float* __restrict__ lc) {
    int rowg = blockIdx.x * 8 + (threadIdx.x >> 5);
    int i = threadIdx.x & 31;
    int b = rowg / 800, r = rowg - b * 800;
    int cap = r / 100, s = r - cap * 100;
    int m = b * 100 + s, co = cap * 32 + i;
    float val = pb[co];
#pragma unroll
    for (int z = 0; z < 8; z++)
        val += __bfloat162float(pp[(z * 6400 + m) * 256 + co]);
    float n2 = val * val;
#pragma unroll
    for (int msk = 1; msk < 32; msk <<= 1) n2 += __shfl_xor(n2, msk);
    float scale = n2 / ((1.f + n2) * sqrtf(n2 + SQ_EPS));
    lc[(b * 800 + r) * 32 + i] = val * scale;
}

// ---------------- u_hat, w kept in registers, b-tiled ---------------------
// grid (100, 4), block 256 = 8 r x 32 (j,o)
__global__ __launch_bounds__(256) void uhat_kernel(
    const float* __restrict__ lc, const float* __restrict__ rw,
    float* __restrict__ uht) {
    int rT = blockIdx.x, bT = blockIdx.y;
    int rl = threadIdx.x >> 5, jo = threadIdx.x & 31;
    int r = rT * 8 + rl;
    float4 wreg[8];
    const float4* wp4 = reinterpret_cast<const float4*>(rw + (r * 32 + jo) * 32);
#pragma unroll
    for (int k = 0; k < 8; k++) wreg[k] = wp4[k];
    for (int b = bT * 16; b < bT * 16 + 16; b++) {
        const float4* lp4 = reinterpret_cast<const float4*>(lc + (b * 800 + r) * 32);
        float acc = 0.f;
#pragma unroll
        for (int k = 0; k < 8; k++) {
            float4 a = lp4[k];
            acc = fmaf(a.x, wreg[k].x, acc);
            acc = fmaf(a.y, wreg[k].y, acc);
            acc = fmaf(a.z, wreg[k].z, acc);
            acc = fmaf(a.w, wreg[k].w, acc);
        }
        uht[(b * 32 + jo) * 800 + r] = acc;
    }
}

// ---------------- routing kernels (unchanged from R1, passed) -------------
__global__ __launch_bounds__(256) void route_sv_kernel(
    const float* __restrict__ uht, const float* __restrict__ bc,
    float* __restrict__ vbuf, float* __restrict__ vout,
    int first_iter, int write_out) {
    int b = blockIdx.y, j = blockIdx.x;
    int tid = threadIdx.x;
    float sp[16];
#pragma unroll
    for (int o = 0; o < 16; o++) sp[o] = 0.f;
    const float* u0 = uht + (b * 32 + j * 16) * 800;
    for (int r = tid; r < 800; r += 256) {
        float c;
        if (first_iter) {
            c = 0.5f;
        } else {
            float b0 = bc[(b * 800 + r) * 2 + 0];
            float b1 = bc[(b * 800 + r) * 2 + 1];
            float m = fmaxf(b0, b1);
            float e0 = __expf(b0 - m), e1 = __expf(b1 - m);
            c = (j == 0 ? e0 : e1) / (e0 + e1);
        }
#pragma unroll
        for (int o = 0; o < 16; o++) sp[o] += c * u0[o * 800 + r];
    }
#pragma unroll
    for (int o = 0; o < 16; o++)
#pragma unroll
        for (int m = 1; m < 64; m <<= 1) sp[o] += __shfl_xor(sp[o], m);
    __shared__ float red[4][16];
    int wave = tid >> 6;
    if ((tid & 63) == 0)
#pragma unroll
        for (int o = 0; o < 16; o++) red[wave][o] = sp[o];
    __syncthreads();
    if (tid == 0) {
        float s[16];
        float n2 = 0.f;
#pragma unroll
        for (int o = 0; o < 16; o++) {
            s[o] = red[0][o] + red[1][o] + red[2][o] + red[3][o];
            n2 += s[o] * s[o];
        }
        float scale = n2 / ((1.f + n2) * sqrtf(n2 + SQ_EPS));
#pragma unroll
        for (int o = 0; o < 16; o++) {
            float v = s[o] * scale;
            vbuf[(b * 2 + j) * 16 + o] = v;
            if (write_out) vout[(b * 2 + j) * 16 + o] = v;
        }
    }
}

__global__ __launch_bounds__(256) void route_bupd_kernel(
    const float* __restrict__ uht, const float* __restrict__ vbuf,
    float* __restrict__ bc) {
    int b = blockIdx.x;
    __shared__ float vs[32];
    if (threadIdx.x < 32) vs[threadIdx.x] = vbuf[b * 32 + threadIdx.x];
    __syncthreads();
    for (int r = threadIdx.x; r < 800; r += 256) {
#pragma unroll
        for (int j = 0; j < 2; j++) {
            float a = 0.f;
#pragma unroll
            for (int o = 0; o < 16; o++)
                a = fmaf(uht[(b * 32 + j * 16 + o) * 800 + r], vs[j * 16 + o], a);
            bc[(b * 800 + r) * 2 + j] += a;
        }
    }
}

extern "C" void kernel_launch(void* const* d_in, const int* in_sizes, int n_in,
                              void* d_out, int out_size, void* d_ws, size_t ws_size,
                              hipStream_t stream) {
    const float* feat    = (const float*)d_in[0];
    const float* conv1_w = (const float*)d_in[1];
    const float* conv1_b = (const float*)d_in[2];
    const float* bn_g    = (const float*)d_in[3];
    const float* bn_b    = (const float*)d_in[4];
    const float* bn_m    = (const float*)d_in[5];
    const float* bn_v    = (const float*)d_in[6];
    const float* prim_w  = (const float*)d_in[7];
    const float* prim_b  = (const float*)d_in[8];
    const float* route_w = (const float*)d_in[9];
    float* out = (float*)d_out;

    // ws layout (bytes); featP region is reused by p_parts/uht/bc/vbuf
    char* wsb = (char*)d_ws;
    bf16*  featP   = (bf16*)(wsb + 0);            // 58,982,400 B (dead after conv1)
    bf16*  p_parts = (bf16*)(wsb + 0);            // 26,214,400 B
    float* uht     = (float*)(wsb + 26214400);    //  6,553,600 B
    float* bc      = (float*)(wsb + 32768000);    //    409,600 B
    float* vbuf    = (float*)(wsb + 33177600);    //      8,192 B
    bf16*  x       = (bf16*)(wsb + 58982400);     // 25,690,112 B
    bf16*  wt1     = (bf16*)(wsb + 84672512);     //  2,359,296 B
    bf16*  wt2     = (bf16*)(wsb + 87031808);     // 10,616,832 B  (end ~97.6 MB)

    float* lc_out = out;                  // (64,800,32)
    float* v_out  = out + 64 * 800 * 32;  // (64,2,16)

    hipMemsetAsync(featP, 0, 58982400, stream);
    feat_to_nhwc<<<dim3(13, 8, 64), 256, 0, stream>>>(feat, featP);
    w1_transform<<<dim3(16, 256), 128, 0, stream>>>(conv1_w, wt1);
    w2_transform<<<dim3(8, 256), 256, 0, stream>>>(prim_w, wt2);

    conv1_mfma<<<dim3(392, 2), 256, 0, stream>>>(
        featP, wt1, conv1_b, bn_g, bn_b, bn_m, bn_v, x);

    conv2_mfma<<<dim3(50, 2, 8), 256, 0, stream>>>(x, wt2, p_parts);

    squash_kernel<<<64 * 800 / 8, 256, 0, stream>>>(p_parts, prim_b, lc_out);

    uhat_kernel<<<dim3(100, 4), 256, 0, stream>>>(lc_out, route_w, uht);

    hipMemsetAsync(bc, 0, 64 * 800 * 2 * sizeof(float), stream);

    route_sv_kernel<<<dim3(2, 64), 256, 0, stream>>>(uht, bc, vbuf, v_out, 1, 0);
    route_bupd_kernel<<<64, 256, 0, stream>>>(uht, vbuf, bc);
    route_sv_kernel<<<dim3(2, 64), 256, 0, stream>>>(uht, bc, vbuf, v_out, 0, 0);
    route_bupd_kernel<<<64, 256, 0, stream>>>(uht, vbuf, bc);
    route_sv_kernel<<<dim3(2, 64), 256, 0, stream>>>(uht, bc, vbuf, v_out, 0, 1);
}

// Round 3
// 354.633 us; speedup vs baseline: 10.6964x; 1.2184x over previous
//
#include <hip/hip_runtime.h>
#include <hip/hip_bf16.h>

#define BN_EPS 1e-5f
#define SQ_EPS 1e-8f

typedef __hip_bfloat16 bf16;
typedef __attribute__((ext_vector_type(8))) short bf16x8;
typedef __attribute__((ext_vector_type(4))) float f32x4;

// async global->LDS, 16B per lane; LDS dest is wave-uniform base + lane*16
__device__ __forceinline__ void gload_lds16(const void* g, void* l) {
    __builtin_amdgcn_global_load_lds(
        (const __attribute__((address_space(1))) unsigned int*)g,
        (__attribute__((address_space(3))) unsigned int*)l, 16, 0, 0);
}

__device__ __forceinline__ unsigned short f2bfu(float f) {
    bf16 h = __float2bfloat16(f);
    return *(unsigned short*)&h;
}

// ---------------- feat NCHW fp32 -> padded NHWC bf16 ----------------------
// featP[64][30][30][512], border pre-zeroed by memset. grid (13,8,64) blk 256
__global__ __launch_bounds__(256) void feat_to_nhwc(
    const float* __restrict__ feat, bf16* __restrict__ featP) {
    int b = blockIdx.z, ct = blockIdx.y, pt = blockIdx.x;
    int ci0 = ct * 64, px0 = pt * 64;
    int tid = threadIdx.x;
    __shared__ float t[64][65];
#pragma unroll
    for (int rep = 0; rep < 16; rep++) {
        int ci_l = rep * 4 + (tid >> 6);
        int px = px0 + (tid & 63);
        float v = 0.f;
        if (px < 784) v = feat[(b * 512 + ci0 + ci_l) * 784 + px];
        t[ci_l][tid & 63] = v;
    }
    __syncthreads();
#pragma unroll
    for (int rep = 0; rep < 4; rep++) {
        int px_l = rep * 16 + (tid >> 4);
        int px = px0 + px_l;
        if (px < 784) {
            int h = px / 28, wq = px % 28;
            int ci = (tid & 15) * 4;
            ushort4 o;
            o.x = f2bfu(t[ci + 0][px_l]);
            o.y = f2bfu(t[ci + 1][px_l]);
            o.z = f2bfu(t[ci + 2][px_l]);
            o.w = f2bfu(t[ci + 3][px_l]);
            *(ushort4*)&featP[((b * 30 + h + 1) * 30 + (wq + 1)) * 512 + ci0 + ci] = o;
        }
    }
}

// ---------------- conv1_w [co][ci][3][3] -> wt1 [kykx][co][ci] bf16 -------
__global__ __launch_bounds__(128) void w1_transform(
    const float* __restrict__ w, bf16* __restrict__ wt1) {
    int co = blockIdx.y, ci0 = blockIdx.x * 32;
    __shared__ float t[288];
    const float* src = w + (co * 512 + ci0) * 9;
    for (int i = threadIdx.x; i < 288; i += 128) t[i] = src[i];
    __syncthreads();
    for (int i = threadIdx.x; i < 288; i += 128) {
        int kykx = i >> 5, ci = i & 31;
        wt1[(kykx * 256 + co) * 512 + ci0 + ci] = __float2bfloat16(t[ci * 9 + kykx]);
    }
}

// ---------------- prim_w [co][ci][9][9] -> wt2 [kykx][co][ci] bf16 --------
__global__ __launch_bounds__(256) void w2_transform(
    const float* __restrict__ w, bf16* __restrict__ wt2) {
    int co = blockIdx.y, ci0 = blockIdx.x * 32;
    __shared__ float t[2592];
    const float* src = w + (co * 256 + ci0) * 81;
    for (int i = threadIdx.x; i < 2592; i += 256) t[i] = src[i];
    __syncthreads();
    for (int i = threadIdx.x; i < 2592; i += 256) {
        int kykx = i >> 5, ci = i & 31;   // 2592 = 81*32
        wt2[(kykx * 256 + co) * 256 + ci0 + ci] = __float2bfloat16(t[ci * 81 + kykx]);
    }
}

// ---------------- conv1 as implicit GEMM (MFMA bf16) ----------------------
// M=50176, N=256, K=9*512. Tile 128x256, BK=32, 4 waves (each 64x128).
// grid 392 (XCD-chunk-swizzled), block 256.
__global__ __launch_bounds__(256, 2) void conv1_mfma(
    const bf16* __restrict__ featP, const bf16* __restrict__ wt1,
    const float* __restrict__ bias, const float* __restrict__ gamma,
    const float* __restrict__ beta, const float* __restrict__ mean,
    const float* __restrict__ var, bf16* __restrict__ x) {
    __shared__ short As[2][4096];   // 128 rows x 32 shorts (64B) per buf
    __shared__ short Bs[2][8192];   // 256 rows x 32 shorts per buf
    const int tid = threadIdx.x, lane = tid & 63, w = tid >> 6;
    const int wr = w >> 1, wc = w & 1;
    const int bid = blockIdx.x;
    const int Mt = (bid & 7) * 49 + (bid >> 3);   // 392 = 8*49, bijective

    // --- staging source pointers (pre-swizzled 16B slot per rule #21) ---
    const bf16 *pA0, *pA1, *pB0, *pB1, *pB2, *pB3;
    {
        int rl0 = w * 32 + (lane >> 2), rl1 = rl0 + 16;
        int q0 = (lane & 3) ^ ((rl0 >> 1) & 3);
        int q1 = (lane & 3) ^ ((rl1 >> 1) & 3);
        int m0 = Mt * 128 + rl0, m1 = Mt * 128 + rl1;
        int b0 = m0 / 784, r0 = m0 % 784, h0 = r0 / 28, w0 = r0 % 28;
        int b1 = m1 / 784, r1 = m1 % 784, h1 = r1 / 28, w1 = r1 % 28;
        pA0 = featP + ((b0 * 30 + h0) * 30 + w0) * 512 + q0 * 8;
        pA1 = featP + ((b1 * 30 + h1) * 30 + w1) * 512 + q1 * 8;
        int rb0 = w * 64 + (lane >> 2);
        int qb0 = (lane & 3) ^ ((rb0 >> 1) & 3);
        int qb1 = (lane & 3) ^ (((rb0 + 16) >> 1) & 3);
        int qb2 = (lane & 3) ^ (((rb0 + 32) >> 1) & 3);
        int qb3 = (lane & 3) ^ (((rb0 + 48) >> 1) & 3);
        pB0 = wt1 + (rb0 +  0) * 512 + qb0 * 8;
        pB1 = wt1 + (rb0 + 16) * 512 + qb1 * 8;
        pB2 = wt1 + (rb0 + 32) * 512 + qb2 * 8;
        pB3 = wt1 + (rb0 + 48) * 512 + qb3 * 8;
    }

    // --- LDS read byte offsets (same swizzle) ---
    int a_off[4], b_off[8];
#pragma unroll
    for (int mi = 0; mi < 4; mi++) {
        int r = wr * 64 + mi * 16 + (lane & 15);
        a_off[mi] = r * 64 + (((lane >> 4) ^ ((r >> 1) & 3)) * 16);
    }
#pragma unroll
    for (int nj = 0; nj < 8; nj++) {
        int r = wc * 128 + nj * 16 + (lane & 15);
        b_off[nj] = r * 64 + (((lane >> 4) ^ ((r >> 1) & 3)) * 16);
    }

    f32x4 acc[4][8];
#pragma unroll
    for (int i = 0; i < 4; i++)
#pragma unroll
        for (int j = 0; j < 8; j++) acc[i][j] = f32x4{0.f, 0.f, 0.f, 0.f};

#define STAGE1(bufi, offE)                                       \
    do {                                                         \
        gload_lds16(pA0 + (offE), &As[bufi][w * 1024]);          \
        gload_lds16(pA1 + (offE), &As[bufi][w * 1024 + 512]);    \
        gload_lds16(pB0 + (offE), &Bs[bufi][w * 2048]);          \
        gload_lds16(pB1 + (offE), &Bs[bufi][w * 2048 + 512]);    \
        gload_lds16(pB2 + (offE), &Bs[bufi][w * 2048 + 1024]);   \
        gload_lds16(pB3 + (offE), &Bs[bufi][w * 2048 + 1536]);   \
    } while (0)

    STAGE1(0, 0);
    __syncthreads();
    int kx = 0;
    for (int g = 0; g < 9; g++) {
#pragma unroll
        for (int c = 0; c < 16; c++) {
            const int cbuf = c & 1;
            if (c < 15) {
                STAGE1(cbuf ^ 1, (c + 1) * 32);
            } else {
                int dA = (kx == 2) ? 28 * 512 : 512;
                kx = (kx == 2) ? 0 : kx + 1;
                pA0 += dA; pA1 += dA;
                pB0 += 131072; pB1 += 131072; pB2 += 131072; pB3 += 131072;
                if (g < 8) STAGE1(cbuf ^ 1, 0);
            }
            bf16x8 af[4], bfr[8];
#pragma unroll
            for (int mi = 0; mi < 4; mi++)
                af[mi] = *(const bf16x8*)((const char*)As + cbuf * 8192 + a_off[mi]);
#pragma unroll
            for (int nj = 0; nj < 8; nj++)
                bfr[nj] = *(const bf16x8*)((const char*)Bs + cbuf * 16384 + b_off[nj]);
#pragma unroll
            for (int mi = 0; mi < 4; mi++)
#pragma unroll
                for (int nj = 0; nj < 8; nj++)
                    acc[mi][nj] = __builtin_amdgcn_mfma_f32_16x16x32_bf16(
                        af[mi], bfr[nj], acc[mi][nj], 0, 0, 0);
            __syncthreads();
        }
    }

    // epilogue: bias + BN + ReLU, write NHWC bf16
#pragma unroll
    for (int nj = 0; nj < 8; nj++) {
        int co = wc * 128 + nj * 16 + (lane & 15);
        float inv = gamma[co] * rsqrtf(var[co] + BN_EPS);
        float sh = beta[co] - mean[co] * inv;
        float bs = bias[co];
#pragma unroll
        for (int mi = 0; mi < 4; mi++) {
            int m0 = Mt * 128 + wr * 64 + mi * 16 + ((lane >> 4) << 2);
#pragma unroll
            for (int r = 0; r < 4; r++) {
                float v = (acc[mi][nj][r] + bs) * inv + sh;
                x[(m0 + r) * 256 + co] = __float2bfloat16(fmaxf(v, 0.f));
            }
        }
    }
#undef STAGE1
}

// ---------------- conv2 (k9 s2) as implicit GEMM, split-K=8 ---------------
// M=6400, N=256, K=81*256. Tile 128x256, 4 waves. grid 400 (swizzled:
// each XCD owns one z so wt2 shell slice stays in its L2).
__global__ __launch_bounds__(256, 2) void conv2_mfma(
    const bf16* __restrict__ x, const bf16* __restrict__ wt2,
    bf16* __restrict__ p_parts) {
    __shared__ short As[2][4096];
    __shared__ short Bs[2][8192];
    const int tid = threadIdx.x, lane = tid & 63, w = tid >> 6;
    const int wr = w >> 1, wc = w & 1;
    const int bid = blockIdx.x;
    const int nid = (bid & 7) * 50 + (bid >> 3);  // 400 = 8*50, bijective
    const int Mt = nid % 50, z = nid / 50;
    const int sh0 = (81 * z) >> 3, sh1 = (81 * (z + 1)) >> 3;

    const bf16 *pA0, *pA1, *pB0, *pB1, *pB2, *pB3;
    {
        int rl0 = w * 32 + (lane >> 2), rl1 = rl0 + 16;
        int q0 = (lane & 3) ^ ((rl0 >> 1) & 3);
        int q1 = (lane & 3) ^ ((rl1 >> 1) & 3);
        int m0 = Mt * 128 + rl0, m1 = Mt * 128 + rl1;
        int b0 = m0 / 100, s0 = m0 % 100, ho0 = s0 / 10, wo0 = s0 % 10;
        int b1 = m1 / 100, s1 = m1 % 100, ho1 = s1 / 10, wo1 = s1 % 10;
        int ky0 = sh0 / 9, kx0 = sh0 % 9;
        pA0 = x + ((b0 * 28 + 2 * ho0 + ky0) * 28 + 2 * wo0 + kx0) * 256 + q0 * 8;
        pA1 = x + ((b1 * 28 + 2 * ho1 + ky0) * 28 + 2 * wo1 + kx0) * 256 + q1 * 8;
        int rb0 = w * 64 + (lane >> 2);
        int qb0 = (lane & 3) ^ ((rb0 >> 1) & 3);
        int qb1 = (lane & 3) ^ (((rb0 + 16) >> 1) & 3);
        int qb2 = (lane & 3) ^ (((rb0 + 32) >> 1) & 3);
        int qb3 = (lane & 3) ^ (((rb0 + 48) >> 1) & 3);
        const bf16* wb = wt2 + sh0 * 65536;
        pB0 = wb + (rb0 +  0) * 256 + qb0 * 8;
        pB1 = wb + (rb0 + 16) * 256 + qb1 * 8;
        pB2 = wb + (rb0 + 32) * 256 + qb2 * 8;
        pB3 = wb + (rb0 + 48) * 256 + qb3 * 8;
    }

    int a_off[4], b_off[8];
#pragma unroll
    for (int mi = 0; mi < 4; mi++) {
        int r = wr * 64 + mi * 16 + (lane & 15);
        a_off[mi] = r * 64 + (((lane >> 4) ^ ((r >> 1) & 3)) * 16);
    }
#pragma unroll
    for (int nj = 0; nj < 8; nj++) {
        int r = wc * 128 + nj * 16 + (lane & 15);
        b_off[nj] = r * 64 + (((lane >> 4) ^ ((r >> 1) & 3)) * 16);
    }

    f32x4 acc[4][8];
#pragma unroll
    for (int i = 0; i < 4; i++)
#pragma unroll
        for (int j = 0; j < 8; j++) acc[i][j] = f32x4{0.f, 0.f, 0.f, 0.f};

#define STAGE2(bufi, offE)                                       \
    do {                                                         \
        gload_lds16(pA0 + (offE), &As[bufi][w * 1024]);          \
        gload_lds16(pA1 + (offE), &As[bufi][w * 1024 + 512]);    \
        gload_lds16(pB0 + (offE), &Bs[bufi][w * 2048]);          \
        gload_lds16(pB1 + (offE), &Bs[bufi][w * 2048 + 512]);    \
        gload_lds16(pB2 + (offE), &Bs[bufi][w * 2048 + 1024]);   \
        gload_lds16(pB3 + (offE), &Bs[bufi][w * 2048 + 1536]);   \
    } while (0)

    STAGE2(0, 0);
    __syncthreads();
    int kx = sh0 % 9;
    for (int g = sh0; g < sh1; g++) {
#pragma unroll
        for (int c = 0; c < 8; c++) {
            const int cbuf = c & 1;
            if (c < 7) {
                STAGE2(cbuf ^ 1, (c + 1) * 32);
            } else {
                int dA = (kx == 8) ? 20 * 256 : 256;
                kx = (kx == 8) ? 0 : kx + 1;
                pA0 += dA; pA1 += dA;
                pB0 += 65536; pB1 += 65536; pB2 += 65536; pB3 += 65536;
                if (g + 1 < sh1) STAGE2(cbuf ^ 1, 0);
            }
            bf16x8 af[4], bfr[8];
#pragma unroll
            for (int mi = 0; mi < 4; mi++)
                af[mi] = *(const bf16x8*)((const char*)As + cbuf * 8192 + a_off[mi]);
#pragma unroll
            for (int nj = 0; nj < 8; nj++)
                bfr[nj] = *(const bf16x8*)((const char*)Bs + cbuf * 16384 + b_off[nj]);
#pragma unroll
            for (int mi = 0; mi < 4; mi++)
#pragma unroll
                for (int nj = 0; nj < 8; nj++)
                    acc[mi][nj] = __builtin_amdgcn_mfma_f32_16x16x32_bf16(
                        af[mi], bfr[nj], acc[mi][nj], 0, 0, 0);
            __syncthreads();
        }
    }

#pragma unroll
    for (int nj = 0; nj < 8; nj++) {
        int co = wc * 128 + nj * 16 + (lane & 15);
#pragma unroll
        for (int mi = 0; mi < 4; mi++) {
            int m0 = Mt * 128 + wr * 64 + mi * 16 + ((lane >> 4) << 2);
#pragma unroll
            for (int r = 0; r < 4; r++)
                p_parts[(z * 6400 + m0 + r) * 256 + co] =
                    __float2bfloat16(acc[mi][nj][r]);
        }
    }
#undef STAGE2
}

// ---------------- squash: sum split-K parts + bias -> lower_caps ----------
__global__ __launch_bounds__(256) void squash_kernel(
    const bf16* __restrict__ pp, const float* __restrict__ pb,
    float* __restrict__ lc) {
    int rowg = blockIdx.x * 8 + (threadIdx.x >> 5);
    int i = threadIdx.x & 31;
    int b = rowg / 800, r = rowg - b * 800;
    int cap = r / 100, s = r - cap * 100;
    int m = b * 100 + s, co = cap * 32 + i;
    float val = pb[co];
#pragma unroll
    for (int z = 0; z < 8; z++)
        val += __bfloat162float(pp[(z * 6400 + m) * 256 + co]);
    float n2 = val * val;
#pragma unroll
    for (int msk = 1; msk < 32; msk <<= 1) n2 += __shfl_xor(n2, msk);
    float scale = n2 / ((1.f + n2) * sqrtf(n2 + SQ_EPS));
    lc[(b * 800 + r) * 32 + i] = val * scale;
}

// ---------------- u_hat, w kept in registers, b-tiled ---------------------
__global__ __launch_bounds__(256) void uhat_kernel(
    const float* __restrict__ lc, const float* __restrict__ rw,
    float* __restrict__ uht) {
    int rT = blockIdx.x, bT = blockIdx.y;
    int rl = threadIdx.x >> 5, jo = threadIdx.x & 31;
    int r = rT * 8 + rl;
    float4 wreg[8];
    const float4* wp4 = reinterpret_cast<const float4*>(rw + (r * 32 + jo) * 32);
#pragma unroll
    for (int k = 0; k < 8; k++) wreg[k] = wp4[k];
    for (int b = bT * 16; b < bT * 16 + 16; b++) {
        const float4* lp4 = reinterpret_cast<const float4*>(lc + (b * 800 + r) * 32);
        float acc = 0.f;
#pragma unroll
        for (int k = 0; k < 8; k++) {
            float4 a = lp4[k];
            acc = fmaf(a.x, wreg[k].x, acc);
            acc = fmaf(a.y, wreg[k].y, acc);
            acc = fmaf(a.z, wreg[k].z, acc);
            acc = fmaf(a.w, wreg[k].w, acc);
        }
        uht[(b * 32 + jo) * 800 + r] = acc;
    }
}

// ---------------- routing kernels -----------------------------------------
__global__ __launch_bounds__(256) void route_sv_kernel(
    const float* __restrict__ uht, const float* __restrict__ bc,
    float* __restrict__ vbuf, float* __restrict__ vout,
    int first_iter, int write_out) {
    int b = blockIdx.y, j = blockIdx.x;
    int tid = threadIdx.x;
    float sp[16];
#pragma unroll
    for (int o = 0; o < 16; o++) sp[o] = 0.f;
    const float* u0 = uht + (b * 32 + j * 16) * 800;
    for (int r = tid; r < 800; r += 256) {
        float c;
        if (first_iter) {
            c = 0.5f;
        } else {
            float b0 = bc[(b * 800 + r) * 2 + 0];
            float b1 = bc[(b * 800 + r) * 2 + 1];
            float m = fmaxf(b0, b1);
            float e0 = __expf(b0 - m), e1 = __expf(b1 - m);
            c = (j == 0 ? e0 : e1) / (e0 + e1);
        }
#pragma unroll
        for (int o = 0; o < 16; o++) sp[o] += c * u0[o * 800 + r];
    }
#pragma unroll
    for (int o = 0; o < 16; o++)
#pragma unroll
        for (int m = 1; m < 64; m <<= 1) sp[o] += __shfl_xor(sp[o], m);
    __shared__ float red[4][16];
    int wave = tid >> 6;
    if ((tid & 63) == 0)
#pragma unroll
        for (int o = 0; o < 16; o++) red[wave][o] = sp[o];
    __syncthreads();
    if (tid == 0) {
        float s[16];
        float n2 = 0.f;
#pragma unroll
        for (int o = 0; o < 16; o++) {
            s[o] = red[0][o] + red[1][o] + red[2][o] + red[3][o];
            n2 += s[o] * s[o];
        }
        float scale = n2 / ((1.f + n2) * sqrtf(n2 + SQ_EPS));
#pragma unroll
        for (int o = 0; o < 16; o++) {
            float v = s[o] * scale;
            vbuf[(b * 2 + j) * 16 + o] = v;
            if (write_out) vout[(b * 2 + j) * 16 + o] = v;
        }
    }
}

__global__ __launch_bounds__(256) void route_bupd_kernel(
    const float* __restrict__ uht, const float* __restrict__ vbuf,
    float* __restrict__ bc) {
    int b = blockIdx.x;
    __shared__ float vs[32];
    if (threadIdx.x < 32) vs[threadIdx.x] = vbuf[b * 32 + threadIdx.x];
    __syncthreads();
    for (int r = threadIdx.x; r < 800; r += 256) {
#pragma unroll
        for (int j = 0; j < 2; j++) {
            float a = 0.f;
#pragma unroll
            for (int o = 0; o < 16; o++)
                a = fmaf(uht[(b * 32 + j * 16 + o) * 800 + r], vs[j * 16 + o], a);
            bc[(b * 800 + r) * 2 + j] += a;
        }
    }
}

extern "C" void kernel_launch(void* const* d_in, const int* in_sizes, int n_in,
                              void* d_out, int out_size, void* d_ws, size_t ws_size,
                              hipStream_t stream) {
    const float* feat    = (const float*)d_in[0];
    const float* conv1_w = (const float*)d_in[1];
    const float* conv1_b = (const float*)d_in[2];
    const float* bn_g    = (const float*)d_in[3];
    const float* bn_b    = (const float*)d_in[4];
    const float* bn_m    = (const float*)d_in[5];
    const float* bn_v    = (const float*)d_in[6];
    const float* prim_w  = (const float*)d_in[7];
    const float* prim_b  = (const float*)d_in[8];
    const float* route_w = (const float*)d_in[9];
    float* out = (float*)d_out;

    char* wsb = (char*)d_ws;
    bf16*  featP   = (bf16*)(wsb + 0);            // 58,982,400 B (dead after conv1)
    bf16*  p_parts = (bf16*)(wsb + 0);            // 26,214,400 B
    float* uht     = (float*)(wsb + 26214400);    //  6,553,600 B
    float* bc      = (float*)(wsb + 32768000);    //    409,600 B
    float* vbuf    = (float*)(wsb + 33177600);    //      8,192 B
    bf16*  x       = (bf16*)(wsb + 58982400);     // 25,690,112 B
    bf16*  wt1     = (bf16*)(wsb + 84672512);     //  2,359,296 B
    bf16*  wt2     = (bf16*)(wsb + 87031808);     // 10,616,832 B

    float* lc_out = out;                  // (64,800,32)
    float* v_out  = out + 64 * 800 * 32;  // (64,2,16)

    hipMemsetAsync(featP, 0, 58982400, stream);
    feat_to_nhwc<<<dim3(13, 8, 64), 256, 0, stream>>>(feat, featP);
    w1_transform<<<dim3(16, 256), 128, 0, stream>>>(conv1_w, wt1);
    w2_transform<<<dim3(8, 256), 256, 0, stream>>>(prim_w, wt2);

    conv1_mfma<<<392, 256, 0, stream>>>(
        featP, wt1, conv1_b, bn_g, bn_b, bn_m, bn_v, x);

    conv2_mfma<<<400, 256, 0, stream>>>(x, wt2, p_parts);

    squash_kernel<<<64 * 800 / 8, 256, 0, stream>>>(p_parts, prim_b, lc_out);

    uhat_kernel<<<dim3(100, 4), 256, 0, stream>>>(lc_out, route_w, uht);

    hipMemsetAsync(bc, 0, 64 * 800 * 2 * sizeof(float), stream);

    route_sv_kernel<<<dim3(2, 64), 256, 0, stream>>>(uht, bc, vbuf, v_out, 1, 0);
    route_bupd_kernel<<<64, 256, 0, stream>>>(uht, vbuf, bc);
    route_sv_kernel<<<dim3(2, 64), 256, 0, stream>>>(uht, bc, vbuf, v_out, 0, 0);
    route_bupd_kernel<<<64, 256, 0, stream>>>(uht, vbuf, bc);
    route_sv_kernel<<<dim3(2, 64), 256, 0, stream>>>(uht, bc, vbuf, v_out, 0, 1);
}

// Round 4
// 311.830 us; speedup vs baseline: 12.1646x; 1.1373x over previous
//
#include <hip/hip_runtime.h>
#include <hip/hip_bf16.h>

#define BN_EPS 1e-5f
#define SQ_EPS 1e-8f

typedef __hip_bfloat16 bf16;
typedef __attribute__((ext_vector_type(8))) short bf16x8;
typedef __attribute__((ext_vector_type(4))) float f32x4;

// async global->LDS, 16B per lane; LDS dest is wave-uniform base + lane*16
__device__ __forceinline__ void gload_lds16(const void* g, void* l) {
    __builtin_amdgcn_global_load_lds(
        (const __attribute__((address_space(1))) unsigned int*)g,
        (__attribute__((address_space(3))) unsigned int*)l, 16, 0, 0);
}

__device__ __forceinline__ unsigned short f2bfu(float f) {
    bf16 h = __float2bfloat16(f);
    return *(unsigned short*)&h;
}

// ---------------- feat NCHW fp32 -> padded NHWC bf16 ----------------------
__global__ __launch_bounds__(256) void feat_to_nhwc(
    const float* __restrict__ feat, bf16* __restrict__ featP) {
    int b = blockIdx.z, ct = blockIdx.y, pt = blockIdx.x;
    int ci0 = ct * 64, px0 = pt * 64;
    int tid = threadIdx.x;
    __shared__ float t[64][65];
#pragma unroll
    for (int rep = 0; rep < 16; rep++) {
        int ci_l = rep * 4 + (tid >> 6);
        int px = px0 + (tid & 63);
        float v = 0.f;
        if (px < 784) v = feat[(b * 512 + ci0 + ci_l) * 784 + px];
        t[ci_l][tid & 63] = v;
    }
    __syncthreads();
#pragma unroll
    for (int rep = 0; rep < 4; rep++) {
        int px_l = rep * 16 + (tid >> 4);
        int px = px0 + px_l;
        if (px < 784) {
            int h = px / 28, wq = px % 28;
            int ci = (tid & 15) * 4;
            ushort4 o;
            o.x = f2bfu(t[ci + 0][px_l]);
            o.y = f2bfu(t[ci + 1][px_l]);
            o.z = f2bfu(t[ci + 2][px_l]);
            o.w = f2bfu(t[ci + 3][px_l]);
            *(ushort4*)&featP[((b * 30 + h + 1) * 30 + (wq + 1)) * 512 + ci0 + ci] = o;
        }
    }
}

// ---------------- conv1_w [co][ci][3][3] -> wt1 [kykx][co][ci] bf16 -------
__global__ __launch_bounds__(128) void w1_transform(
    const float* __restrict__ w, bf16* __restrict__ wt1) {
    int co = blockIdx.y, ci0 = blockIdx.x * 32;
    __shared__ float t[288];
    const float* src = w + (co * 512 + ci0) * 9;
    for (int i = threadIdx.x; i < 288; i += 128) t[i] = src[i];
    __syncthreads();
    for (int i = threadIdx.x; i < 288; i += 128) {
        int kykx = i >> 5, ci = i & 31;
        wt1[(kykx * 256 + co) * 512 + ci0 + ci] = __float2bfloat16(t[ci * 9 + kykx]);
    }
}

// ---------------- prim_w [co][ci][9][9] -> wt2 [kykx][co][ci] bf16 --------
__global__ __launch_bounds__(256) void w2_transform(
    const float* __restrict__ w, bf16* __restrict__ wt2) {
    int co = blockIdx.y, ci0 = blockIdx.x * 32;
    __shared__ float t[2592];
    const float* src = w + (co * 256 + ci0) * 81;
    for (int i = threadIdx.x; i < 2592; i += 256) t[i] = src[i];
    __syncthreads();
    for (int i = threadIdx.x; i < 2592; i += 256) {
        int kykx = i >> 5, ci = i & 31;
        wt2[(kykx * 256 + co) * 256 + ci0 + ci] = __float2bfloat16(t[ci * 81 + kykx]);
    }
}

// ---------------- conv1: 256x256 tile, 8 waves, 4-region rolling pipe -----
// M=50176, N=256, K=9*512 -> 144 BK=32 tiles. grid 196, block 512.
// LDS 128KB: A 4x16KB | B 4x16KB. Stage t+3 while computing t; vmcnt(8).
__global__ __launch_bounds__(512, 2) void conv1_mfma(
    const bf16* __restrict__ featP, const bf16* __restrict__ wt1,
    const float* __restrict__ bias, const float* __restrict__ gamma,
    const float* __restrict__ beta, const float* __restrict__ mean,
    const float* __restrict__ var, bf16* __restrict__ x) {
    extern __shared__ char smem[];           // [0,64K)=A bufs, [64K,128K)=B
    const int tid = threadIdx.x, lane = tid & 63, w = tid >> 6;
    const int wr = w >> 2, wc = w & 3;       // 2 x 4 wave grid, wave = 128x64
    const int xcd = blockIdx.x & 7, ix = blockIdx.x >> 3;
    const int Mt = (xcd < 4 ? xcd * 25 : 100 + (xcd - 4) * 24) + ix; // m204 bijective

    const bf16 *pA0, *pA1, *pB0, *pB1;
    {
        int r0 = (w << 4) + (lane >> 2);               // rows 0..127 (j=0)
        int q = (lane & 3) ^ ((r0 >> 1) & 3);          // same swz for r0+128
        int m0 = Mt * 256 + r0;
        int b0 = m0 / 784, rr = m0 % 784, h0 = rr / 28, w0 = rr % 28;
        pA0 = featP + ((b0 * 30 + h0) * 30 + w0) * 512 + q * 8;
        int m1 = m0 + 128;
        int b1 = m1 / 784, rr1 = m1 % 784, h1 = rr1 / 28, w1 = rr1 % 28;
        pA1 = featP + ((b1 * 30 + h1) * 30 + w1) * 512 + q * 8;
        pB0 = wt1 + r0 * 512 + q * 8;
        pB1 = pB0 + 128 * 512;
    }

    int a_off[8], b_off[4];
#pragma unroll
    for (int mi = 0; mi < 8; mi++) {
        int r = wr * 128 + mi * 16 + (lane & 15);
        a_off[mi] = r * 64 + (((lane >> 4) ^ ((r >> 1) & 3)) * 16);
    }
#pragma unroll
    for (int nj = 0; nj < 4; nj++) {
        int r = wc * 64 + nj * 16 + (lane & 15);
        b_off[nj] = r * 64 + (((lane >> 4) ^ ((r >> 1) & 3)) * 16);
    }

    f32x4 acc[8][4];
#pragma unroll
    for (int i = 0; i < 8; i++)
#pragma unroll
        for (int j = 0; j < 4; j++) acc[i][j] = f32x4{0.f, 0.f, 0.f, 0.f};

#define STG_A1(bi, oA)                                                      \
    do {                                                                    \
        gload_lds16(pA0 + (oA), smem + (bi) * 16384 + w * 1024);            \
        gload_lds16(pA1 + (oA), smem + (bi) * 16384 + 8192 + w * 1024);     \
    } while (0)
#define STG_B1(bi, oB)                                                      \
    do {                                                                    \
        gload_lds16(pB0 + (oB), smem + 65536 + (bi) * 16384 + w * 1024);    \
        gload_lds16(pB1 + (oB), smem + 65536 + (bi) * 16384 + 8192 + w * 1024); \
    } while (0)

    // prologue: stage tiles 0,1,2 (shell 0, ci-chunks 0,1,2)
    STG_A1(0, 0);  STG_B1(0, 0);
    STG_A1(1, 32); STG_B1(1, 32);
    STG_A1(2, 64); STG_B1(2, 64);
    asm volatile("s_waitcnt vmcnt(8)" ::: "memory");  // tile0 landed
    __builtin_amdgcn_s_barrier();
    asm volatile("" ::: "memory");

    for (int t = 0; t < 144; t += 4) {
#pragma unroll
        for (int u = 0; u < 4; u++) {
            const int cur = u, stg = (u + 3) & 3;     // t%4==0 -> compile-time
            const int tt = t + u + 3;
            const char* Ab = smem + cur * 16384;
            const char* Bb = smem + 65536 + cur * 16384;
            if (tt < 144) {
                int g = tt >> 4, cc = tt & 15;
                int ky = g / 3, kx = g - ky * 3;
                STG_A1(stg, (ky * 30 + kx) * 512 + cc * 32);
            }
            bf16x8 af[8];
#pragma unroll
            for (int mi = 0; mi < 8; mi++)
                af[mi] = *(const bf16x8*)(Ab + a_off[mi]);
            bf16x8 b0v = *(const bf16x8*)(Bb + b_off[0]);
            bf16x8 b1v = *(const bf16x8*)(Bb + b_off[1]);
            __builtin_amdgcn_s_setprio(1);
#pragma unroll
            for (int mi = 0; mi < 8; mi++)
                acc[mi][0] = __builtin_amdgcn_mfma_f32_16x16x32_bf16(af[mi], b0v, acc[mi][0], 0, 0, 0);
#pragma unroll
            for (int mi = 0; mi < 8; mi++)
                acc[mi][1] = __builtin_amdgcn_mfma_f32_16x16x32_bf16(af[mi], b1v, acc[mi][1], 0, 0, 0);
            __builtin_amdgcn_s_setprio(0);
            if (tt < 144) {
                int g = tt >> 4, cc = tt & 15;
                STG_B1(stg, g * 131072 + cc * 32);
            }
            bf16x8 b2v = *(const bf16x8*)(Bb + b_off[2]);
            bf16x8 b3v = *(const bf16x8*)(Bb + b_off[3]);
            __builtin_amdgcn_s_setprio(1);
#pragma unroll
            for (int mi = 0; mi < 8; mi++)
                acc[mi][2] = __builtin_amdgcn_mfma_f32_16x16x32_bf16(af[mi], b2v, acc[mi][2], 0, 0, 0);
#pragma unroll
            for (int mi = 0; mi < 8; mi++)
                acc[mi][3] = __builtin_amdgcn_mfma_f32_16x16x32_bf16(af[mi], b3v, acc[mi][3], 0, 0, 0);
            __builtin_amdgcn_s_setprio(0);
            // boundary: tile t+1's stages (issued at t-2) must be landed.
            if (tt < 144) asm volatile("s_waitcnt vmcnt(8)" ::: "memory");
            else          asm volatile("s_waitcnt vmcnt(0)" ::: "memory");
            __builtin_amdgcn_s_barrier();
            asm volatile("" ::: "memory");
        }
    }

#pragma unroll
    for (int nj = 0; nj < 4; nj++) {
        int co = wc * 64 + nj * 16 + (lane & 15);
        float inv = gamma[co] * rsqrtf(var[co] + BN_EPS);
        float sh = beta[co] - mean[co] * inv;
        float bs = bias[co];
#pragma unroll
        for (int mi = 0; mi < 8; mi++) {
            int m0 = Mt * 256 + wr * 128 + mi * 16 + ((lane >> 4) << 2);
#pragma unroll
            for (int r = 0; r < 4; r++) {
                float v = (acc[mi][nj][r] + bs) * inv + sh;
                x[(m0 + r) * 256 + co] = __float2bfloat16(fmaxf(v, 0.f));
            }
        }
    }
#undef STG_A1
#undef STG_B1
}

// ---------------- conv2 (k9 s2): same template, split-K=8 -----------------
// M=6400, N=256. grid 200 (z=bid&7 pinned per-XCD), block 512.
__global__ __launch_bounds__(512, 2) void conv2_mfma(
    const bf16* __restrict__ x, const bf16* __restrict__ wt2,
    bf16* __restrict__ p_parts) {
    extern __shared__ char smem[];
    const int tid = threadIdx.x, lane = tid & 63, w = tid >> 6;
    const int wr = w >> 2, wc = w & 3;
    const int z = blockIdx.x & 7, Mt = blockIdx.x >> 3;
    const int sh0 = (81 * z) >> 3, sh1 = (81 * (z + 1)) >> 3;
    const int NT = (sh1 - sh0) << 3;          // 80 or 88 BK=32 tiles

    const bf16 *pA0, *pA1, *pB0, *pB1;
    {
        int r0 = (w << 4) + (lane >> 2);
        int q = (lane & 3) ^ ((r0 >> 1) & 3);
        int m0 = Mt * 256 + r0;
        int b0 = m0 / 100, s0 = m0 % 100, ho0 = s0 / 10, wo0 = s0 % 10;
        pA0 = x + ((b0 * 28 + 2 * ho0) * 28 + 2 * wo0) * 256 + q * 8;
        int m1 = m0 + 128;
        int b1 = m1 / 100, s1 = m1 % 100, ho1 = s1 / 10, wo1 = s1 % 10;
        pA1 = x + ((b1 * 28 + 2 * ho1) * 28 + 2 * wo1) * 256 + q * 8;
        pB0 = wt2 + r0 * 256 + q * 8;
        pB1 = pB0 + 128 * 256;
    }

    int a_off[8], b_off[4];
#pragma unroll
    for (int mi = 0; mi < 8; mi++) {
        int r = wr * 128 + mi * 16 + (lane & 15);
        a_off[mi] = r * 64 + (((lane >> 4) ^ ((r >> 1) & 3)) * 16);
    }
#pragma unroll
    for (int nj = 0; nj < 4; nj++) {
        int r = wc * 64 + nj * 16 + (lane & 15);
        b_off[nj] = r * 64 + (((lane >> 4) ^ ((r >> 1) & 3)) * 16);
    }

    f32x4 acc[8][4];
#pragma unroll
    for (int i = 0; i < 8; i++)
#pragma unroll
        for (int j = 0; j < 4; j++) acc[i][j] = f32x4{0.f, 0.f, 0.f, 0.f};

#define STG_A2(bi, oA)                                                      \
    do {                                                                    \
        gload_lds16(pA0 + (oA), smem + (bi) * 16384 + w * 1024);            \
        gload_lds16(pA1 + (oA), smem + (bi) * 16384 + 8192 + w * 1024);     \
    } while (0)
#define STG_B2(bi, oB)                                                      \
    do {                                                                    \
        gload_lds16(pB0 + (oB), smem + 65536 + (bi) * 16384 + w * 1024);    \
        gload_lds16(pB1 + (oB), smem + 65536 + (bi) * 16384 + 8192 + w * 1024); \
    } while (0)

    {
        int ky0 = sh0 / 9, kx0 = sh0 - 9 * ky0;
        int oA0 = (ky0 * 28 + kx0) * 256;
        int oB0 = sh0 * 65536;
        STG_A2(0, oA0);      STG_B2(0, oB0);
        STG_A2(1, oA0 + 32); STG_B2(1, oB0 + 32);
        STG_A2(2, oA0 + 64); STG_B2(2, oB0 + 64);
    }
    asm volatile("s_waitcnt vmcnt(8)" ::: "memory");
    __builtin_amdgcn_s_barrier();
    asm volatile("" ::: "memory");

    for (int t = 0; t < NT; t += 4) {
#pragma unroll
        for (int u = 0; u < 4; u++) {
            const int cur = u, stg = (u + 3) & 3;
            const int tt = t + u + 3;
            const char* Ab = smem + cur * 16384;
            const char* Bb = smem + 65536 + cur * 16384;
            if (tt < NT) {
                int sh = sh0 + (tt >> 3), cc = tt & 7;
                int ky = sh / 9, kx = sh - 9 * ky;
                STG_A2(stg, (ky * 28 + kx) * 256 + cc * 32);
            }
            bf16x8 af[8];
#pragma unroll
            for (int mi = 0; mi < 8; mi++)
                af[mi] = *(const bf16x8*)(Ab + a_off[mi]);
            bf16x8 b0v = *(const bf16x8*)(Bb + b_off[0]);
            bf16x8 b1v = *(const bf16x8*)(Bb + b_off[1]);
            __builtin_amdgcn_s_setprio(1);
#pragma unroll
            for (int mi = 0; mi < 8; mi++)
                acc[mi][0] = __builtin_amdgcn_mfma_f32_16x16x32_bf16(af[mi], b0v, acc[mi][0], 0, 0, 0);
#pragma unroll
            for (int mi = 0; mi < 8; mi++)
                acc[mi][1] = __builtin_amdgcn_mfma_f32_16x16x32_bf16(af[mi], b1v, acc[mi][1], 0, 0, 0);
            __builtin_amdgcn_s_setprio(0);
            if (tt < NT) {
                int sh = sh0 + (tt >> 3), cc = tt & 7;
                STG_B2(stg, sh * 65536 + cc * 32);
            }
            bf16x8 b2v = *(const bf16x8*)(Bb + b_off[2]);
            bf16x8 b3v = *(const bf16x8*)(Bb + b_off[3]);
            __builtin_amdgcn_s_setprio(1);
#pragma unroll
            for (int mi = 0; mi < 8; mi++)
                acc[mi][2] = __builtin_amdgcn_mfma_f32_16x16x32_bf16(af[mi], b2v, acc[mi][2], 0, 0, 0);
#pragma unroll
            for (int mi = 0; mi < 8; mi++)
                acc[mi][3] = __builtin_amdgcn_mfma_f32_16x16x32_bf16(af[mi], b3v, acc[mi][3], 0, 0, 0);
            __builtin_amdgcn_s_setprio(0);
            if (tt < NT) asm volatile("s_waitcnt vmcnt(8)" ::: "memory");
            else         asm volatile("s_waitcnt vmcnt(0)" ::: "memory");
            __builtin_amdgcn_s_barrier();
            asm volatile("" ::: "memory");
        }
    }

#pragma unroll
    for (int nj = 0; nj < 4; nj++) {
        int co = wc * 64 + nj * 16 + (lane & 15);
#pragma unroll
        for (int mi = 0; mi < 8; mi++) {
            int m0 = Mt * 256 + wr * 128 + mi * 16 + ((lane >> 4) << 2);
#pragma unroll
            for (int r = 0; r < 4; r++)
                p_parts[(z * 6400 + m0 + r) * 256 + co] =
                    __float2bfloat16(acc[mi][nj][r]);
        }
    }
#undef STG_A2
#undef STG_B2
}

// ---------------- squash: sum split-K parts + bias -> lower_caps ----------
__global__ __launch_bounds__(256) void squash_kernel(
    const bf16* __restrict__ pp, const float* __restrict__ pb,
    float* __restrict__ lc) {
    int rowg = blockIdx.x * 8 + (threadIdx.x >> 5);
    int i = threadIdx.x & 31;
    int b = rowg / 800, r = rowg - b * 800;
    int cap = r / 100, s = r - cap * 100;
    int m = b * 100 + s, co = cap * 32 + i;
    float val = pb[co];
#pragma unroll
    for (int z = 0; z < 8; z++)
        val += __bfloat162float(pp[(z * 6400 + m) * 256 + co]);
    float n2 = val * val;
#pragma unroll
    for (int msk = 1; msk < 32; msk <<= 1) n2 += __shfl_xor(n2, msk);
    float scale = n2 / ((1.f + n2) * sqrtf(n2 + SQ_EPS));
    lc[(b * 800 + r) * 32 + i] = val * scale;
}

// ---------------- u_hat, w kept in registers, b-tiled ---------------------
__global__ __launch_bounds__(256) void uhat_kernel(
    const float* __restrict__ lc, const float* __restrict__ rw,
    float* __restrict__ uht) {
    int rT = blockIdx.x, bT = blockIdx.y;
    int rl = threadIdx.x >> 5, jo = threadIdx.x & 31;
    int r = rT * 8 + rl;
    float4 wreg[8];
    const float4* wp4 = reinterpret_cast<const float4*>(rw + (r * 32 + jo) * 32);
#pragma unroll
    for (int k = 0; k < 8; k++) wreg[k] = wp4[k];
    for (int b = bT * 16; b < bT * 16 + 16; b++) {
        const float4* lp4 = reinterpret_cast<const float4*>(lc + (b * 800 + r) * 32);
        float acc = 0.f;
#pragma unroll
        for (int k = 0; k < 8; k++) {
            float4 a = lp4[k];
            acc = fmaf(a.x, wreg[k].x, acc);
            acc = fmaf(a.y, wreg[k].y, acc);
            acc = fmaf(a.z, wreg[k].z, acc);
            acc = fmaf(a.w, wreg[k].w, acc);
        }
        uht[(b * 32 + jo) * 800 + r] = acc;
    }
}

// ---------------- routing kernels -----------------------------------------
__global__ __launch_bounds__(256) void route_sv_kernel(
    const float* __restrict__ uht, const float* __restrict__ bc,
    float* __restrict__ vbuf, float* __restrict__ vout,
    int first_iter, int write_out) {
    int b = blockIdx.y, j = blockIdx.x;
    int tid = threadIdx.x;
    float sp[16];
#pragma unroll
    for (int o = 0; o < 16; o++) sp[o] = 0.f;
    const float* u0 = uht + (b * 32 + j * 16) * 800;
    for (int r = tid; r < 800; r += 256) {
        float c;
        if (first_iter) {
            c = 0.5f;
        } else {
            float b0 = bc[(b * 800 + r) * 2 + 0];
            float b1 = bc[(b * 800 + r) * 2 + 1];
            float m = fmaxf(b0, b1);
            float e0 = __expf(b0 - m), e1 = __expf(b1 - m);
            c = (j == 0 ? e0 : e1) / (e0 + e1);
        }
#pragma unroll
        for (int o = 0; o < 16; o++) sp[o] += c * u0[o * 800 + r];
    }
#pragma unroll
    for (int o = 0; o < 16; o++)
#pragma unroll
        for (int m = 1; m < 64; m <<= 1) sp[o] += __shfl_xor(sp[o], m);
    __shared__ float red[4][16];
    int wave = tid >> 6;
    if ((tid & 63) == 0)
#pragma unroll
        for (int o = 0; o < 16; o++) red[wave][o] = sp[o];
    __syncthreads();
    if (tid == 0) {
        float s[16];
        float n2 = 0.f;
#pragma unroll
        for (int o = 0; o < 16; o++) {
            s[o] = red[0][o] + red[1][o] + red[2][o] + red[3][o];
            n2 += s[o] * s[o];
        }
        float scale = n2 / ((1.f + n2) * sqrtf(n2 + SQ_EPS));
#pragma unroll
        for (int o = 0; o < 16; o++) {
            float v = s[o] * scale;
            vbuf[(b * 2 + j) * 16 + o] = v;
            if (write_out) vout[(b * 2 + j) * 16 + o] = v;
        }
    }
}

__global__ __launch_bounds__(256) void route_bupd_kernel(
    const float* __restrict__ uht, const float* __restrict__ vbuf,
    float* __restrict__ bc) {
    int b = blockIdx.x;
    __shared__ float vs[32];
    if (threadIdx.x < 32) vs[threadIdx.x] = vbuf[b * 32 + threadIdx.x];
    __syncthreads();
    for (int r = threadIdx.x; r < 800; r += 256) {
#pragma unroll
        for (int j = 0; j < 2; j++) {
            float a = 0.f;
#pragma unroll
            for (int o = 0; o < 16; o++)
                a = fmaf(uht[(b * 32 + j * 16 + o) * 800 + r], vs[j * 16 + o], a);
            bc[(b * 800 + r) * 2 + j] += a;
        }
    }
}

extern "C" void kernel_launch(void* const* d_in, const int* in_sizes, int n_in,
                              void* d_out, int out_size, void* d_ws, size_t ws_size,
                              hipStream_t stream) {
    const float* feat    = (const float*)d_in[0];
    const float* conv1_w = (const float*)d_in[1];
    const float* conv1_b = (const float*)d_in[2];
    const float* bn_g    = (const float*)d_in[3];
    const float* bn_b    = (const float*)d_in[4];
    const float* bn_m    = (const float*)d_in[5];
    const float* bn_v    = (const float*)d_in[6];
    const float* prim_w  = (const float*)d_in[7];
    const float* prim_b  = (const float*)d_in[8];
    const float* route_w = (const float*)d_in[9];
    float* out = (float*)d_out;

    char* wsb = (char*)d_ws;
    bf16*  featP   = (bf16*)(wsb + 0);            // 58,982,400 B (dead after conv1)
    bf16*  p_parts = (bf16*)(wsb + 0);            // 26,214,400 B
    float* uht     = (float*)(wsb + 26214400);    //  6,553,600 B
    float* bc      = (float*)(wsb + 32768000);    //    409,600 B
    float* vbuf    = (float*)(wsb + 33177600);    //      8,192 B
    bf16*  x       = (bf16*)(wsb + 58982400);     // 25,690,112 B
    bf16*  wt1     = (bf16*)(wsb + 84672512);     //  2,359,296 B
    bf16*  wt2     = (bf16*)(wsb + 87031808);     // 10,616,832 B

    float* lc_out = out;                  // (64,800,32)
    float* v_out  = out + 64 * 800 * 32;  // (64,2,16)

    // allow 128 KiB dynamic LDS (idempotent host-side calls, capture-safe)
    hipFuncSetAttribute((const void*)conv1_mfma,
                        hipFuncAttributeMaxDynamicSharedMemorySize, 131072);
    hipFuncSetAttribute((const void*)conv2_mfma,
                        hipFuncAttributeMaxDynamicSharedMemorySize, 131072);

    hipMemsetAsync(featP, 0, 58982400, stream);
    feat_to_nhwc<<<dim3(13, 8, 64), 256, 0, stream>>>(feat, featP);
    w1_transform<<<dim3(16, 256), 128, 0, stream>>>(conv1_w, wt1);
    w2_transform<<<dim3(8, 256), 256, 0, stream>>>(prim_w, wt2);

    conv1_mfma<<<196, 512, 131072, stream>>>(
        featP, wt1, conv1_b, bn_g, bn_b, bn_m, bn_v, x);

    conv2_mfma<<<200, 512, 131072, stream>>>(x, wt2, p_parts);

    squash_kernel<<<64 * 800 / 8, 256, 0, stream>>>(p_parts, prim_b, lc_out);

    uhat_kernel<<<dim3(100, 4), 256, 0, stream>>>(lc_out, route_w, uht);

    hipMemsetAsync(bc, 0, 64 * 800 * 2 * sizeof(float), stream);

    route_sv_kernel<<<dim3(2, 64), 256, 0, stream>>>(uht, bc, vbuf, v_out, 1, 0);
    route_bupd_kernel<<<64, 256, 0, stream>>>(uht, vbuf, bc);
    route_sv_kernel<<<dim3(2, 64), 256, 0, stream>>>(uht, bc, vbuf, v_out, 0, 0);
    route_bupd_kernel<<<64, 256, 0, stream>>>(uht, vbuf, bc);
    route_sv_kernel<<<dim3(2, 64), 256, 0, stream>>>(uht, bc, vbuf, v_out, 0, 1);
}